// Round 6
// baseline (428.376 us; speedup 1.0000x reference)
//
#include <hip/hip_runtime.h>
#include <hip/hip_fp16.h>
#include <hip/hip_bf16.h>

#define SLOPE 0.2f
#define LDA 136    // padded LDS row (bf16 elems): 272B stride -> 2-way-free banks

typedef short bf16x8 __attribute__((ext_vector_type(8)));
typedef float f32x4 __attribute__((ext_vector_type(4)));

__device__ __forceinline__ unsigned short f2bf(float x) {
    unsigned u = __float_as_uint(x);
    u += 0x7FFFu + ((u >> 16) & 1u);     // RNE
    return (unsigned short)(u >> 16);
}

// ---------------------------------------------------------------------------
// prep fused: blocks 0..63 W_src->bf16^T, 64..127 W_dst->bf16^T, 128 attn,
// 129.. degree atomics (deg pre-zeroed by memset on same stream).
// ---------------------------------------------------------------------------
__global__ void prep_kernel(const float* __restrict__ feat_rel,
                            const float* __restrict__ W_rel,
                            const float* __restrict__ b_rel,
                            float* __restrict__ attn,
                            const float* __restrict__ W_src,
                            unsigned short* __restrict__ WtS,
                            const float* __restrict__ W_dst,
                            unsigned short* __restrict__ WtD,
                            const int* __restrict__ dst_idx,
                            int* __restrict__ deg, int ne) {
    int bx = blockIdx.x;
    if (bx < 128) {
        const float* W = (bx < 64) ? W_src : W_dst;
        unsigned short* Wt = (bx < 64) ? WtS : WtD;
        int t = (bx & 63) * 256 + threadIdx.x;   // 16384
        int n = t >> 7, k = t & 127;
        Wt[n * 128 + k] = f2bf(W[k * 128 + n]);
    } else if (bx == 128) {
        int j = threadIdx.x;            // 0..255
        float acc = b_rel[j];
        for (int d = 0; d < 128; ++d)
            acc = fmaf(feat_rel[d], W_rel[d * 256 + j], acc);
        attn[j] = acc;
    } else {
        int e = (bx - 129) * 256 + threadIdx.x;
        if (e < ne) atomicAdd(&deg[dst_idx[e]], 1);
    }
}

// ---------------------------------------------------------------------------
// MFMA GEMM (both projections in one launch): blocks [0,nbs) do feat_src,
// [nbs,..) feat_dst. 64 rows x 128 cols per block, fused epilogue:
// fs fp16 store + e[row][h] = sum_d f*attn. 4 waves; wave wv owns cols wv*32..+31.
// mfma_f32_16x16x32_bf16: C/D col=lane&15, row=quad*4+reg (m89-verified).
// ---------------------------------------------------------------------------
__global__ __launch_bounds__(256) void gemm_mfma_kernel(
    const float* __restrict__ featS, const unsigned short* __restrict__ WtS,
    const float* __restrict__ bS,
    const float* __restrict__ featD, const unsigned short* __restrict__ WtD,
    const float* __restrict__ bD,
    const float* __restrict__ attn, __half* __restrict__ fs,
    float* __restrict__ el, float* __restrict__ er,
    int Ms, int Md, int nbs)
{
    __shared__ unsigned short sA[64 * LDA];    // [row][k] bf16
    __shared__ unsigned short sB[128 * LDA];   // [n][k]  bf16

    int bx = blockIdx.x;
    const float* feat; const unsigned short* Wt; const float* bias;
    __half* f_out; float* e_out; int attn_off, M, row0;
    if (bx < nbs) {
        feat = featS; Wt = WtS; bias = bS; f_out = fs; e_out = el;
        attn_off = 0; M = Ms; row0 = bx * 64;
    } else {
        feat = featD; Wt = WtD; bias = bD; f_out = nullptr; e_out = er;
        attn_off = 16; M = Md; row0 = (bx - nbs) * 64;
    }

    int t = threadIdx.x;

    // stage A: 64x128 fp32 -> bf16; 2048 float4s / 256 thr = 8 each
#pragma unroll
    for (int i = 0; i < 8; ++i) {
        int idx = t + i * 256;
        int row = idx >> 5, k4 = idx & 31;
        int grow = row0 + row;
        float4 v = {0.f, 0.f, 0.f, 0.f};
        if (grow < M) v = *(const float4*)(feat + (size_t)grow * 128 + k4 * 4);
        ushort4 b;
        b.x = f2bf(v.x); b.y = f2bf(v.y); b.z = f2bf(v.z); b.w = f2bf(v.w);
        *(ushort4*)&sA[row * LDA + k4 * 4] = b;   // 8B aligned (272B rows)
    }
    // stage B: Wt bf16 128x128 -> padded LDS; 2048 16B chunks / 256 = 8 each
#pragma unroll
    for (int i = 0; i < 8; ++i) {
        int idx = t + i * 256;
        int n = idx >> 4, koff = (idx & 15) * 8;
        *(uint4*)&sB[n * LDA + koff] = *(const uint4*)&Wt[n * 128 + koff];
    }
    __syncthreads();

    int wv = t >> 6, lane = t & 63;
    int m = lane & 15, quad = lane >> 4;
    int n0 = wv * 32;

    f32x4 acc[2][4];
#pragma unroll
    for (int ct = 0; ct < 2; ++ct)
#pragma unroll
        for (int rt = 0; rt < 4; ++rt) acc[ct][rt] = (f32x4){0.f, 0.f, 0.f, 0.f};

#pragma unroll
    for (int ks = 0; ks < 4; ++ks) {
        bf16x8 a[4], b[2];
#pragma unroll
        for (int rt = 0; rt < 4; ++rt)
            a[rt] = *(const bf16x8*)&sA[(rt * 16 + m) * LDA + ks * 32 + quad * 8];
#pragma unroll
        for (int ct = 0; ct < 2; ++ct)
            b[ct] = *(const bf16x8*)&sB[(n0 + ct * 16 + m) * LDA + ks * 32 + quad * 8];
#pragma unroll
        for (int ct = 0; ct < 2; ++ct)
#pragma unroll
            for (int rt = 0; rt < 4; ++rt)
                acc[ct][rt] = __builtin_amdgcn_mfma_f32_16x16x32_bf16(
                    a[rt], b[ct], acc[ct][rt], 0, 0, 0);
    }

    // epilogue
#pragma unroll
    for (int ct = 0; ct < 2; ++ct) {
        int gcol = n0 + ct * 16 + m;
        int h = gcol >> 4;
        float bias_v = bias[gcol];
        float attn_v = attn[h * 32 + attn_off + (gcol & 15)];
#pragma unroll
        for (int rt = 0; rt < 4; ++rt) {
            f32x4 c = acc[ct][rt];
#pragma unroll
            for (int r = 0; r < 4; ++r) {
                float v = c[r] + bias_v;
                int grow = row0 + rt * 16 + quad * 4 + r;
                float p = v * attn_v;
                p += __shfl_xor(p, 1);
                p += __shfl_xor(p, 2);
                p += __shfl_xor(p, 4);
                p += __shfl_xor(p, 8);
                if (grow < M) {
                    if (f_out) f_out[(size_t)grow * 128 + gcol] = __float2half(v);
                    if (m == 0) e_out[(size_t)grow * 8 + h] = p;
                }
            }
        }
    }
}

// ---------------------------------------------------------------------------
// CSR offsets: scan over deg
// ---------------------------------------------------------------------------
__global__ void scan1(const int* __restrict__ deg, int* __restrict__ excl,
                      int* __restrict__ bsum, int n) {
    __shared__ int tmp[256];
    int t = threadIdx.x;
    int i = blockIdx.x * 256 + t;
    int v = (i < n) ? deg[i] : 0;
    tmp[t] = v;
    __syncthreads();
    for (int off = 1; off < 256; off <<= 1) {
        int x = 0;
        if (t >= off) x = tmp[t - off];
        __syncthreads();
        tmp[t] += x;
        __syncthreads();
    }
    if (i < n) excl[i] = tmp[t] - v;
    if (t == 255) bsum[blockIdx.x] = tmp[255];
}

__global__ void scan2(int* __restrict__ bsum, int nb) {
    __shared__ int tmp[512];
    int t = threadIdx.x;
    int v = (t < nb) ? bsum[t] : 0;
    tmp[t] = v;
    __syncthreads();
    for (int off = 1; off < 512; off <<= 1) {
        int x = 0;
        if (t >= off) x = tmp[t - off];
        __syncthreads();
        tmp[t] += x;
        __syncthreads();
    }
    if (t < nb) bsum[t] = tmp[t] - v;
}

__global__ void scan3(const int* __restrict__ excl, const int* __restrict__ bsum,
                      int* __restrict__ roff, int n) {
    int i = blockIdx.x * 256 + threadIdx.x;
    if (i < n) roff[i] = excl[i] + bsum[blockIdx.x];
}

// ---------------------------------------------------------------------------
// CSR scatter (csr only — no wE, so the R3 write-amp trap doesn't apply:
// 4B writes into a 6.4MB array are absorbed by per-XCD L2 write-back).
// Same atomic pattern as degree_kernel (proven cheap).
// ---------------------------------------------------------------------------
__global__ __launch_bounds__(256) void scatter_kernel(
    const int* __restrict__ src_idx, const int* __restrict__ dst_idx,
    const int* __restrict__ roff, int* __restrict__ ncur,
    int* __restrict__ csr, int ne)
{
    int e = blockIdx.x * 256 + threadIdx.x;
    if (e >= ne) return;
    int s = src_idx[e], d = dst_idx[e];
    int p = roff[d] + atomicAdd(&ncur[d], 1);
    csr[p] = s;
}

// ---------------------------------------------------------------------------
// Aggregation: 16 lanes per dst node (4 nodes/wave, 16 nodes/block).
// Lane q owns dims [q*8,q*8+8) -> one dwordx4 gather/edge/lane; head = q>>1.
// Edge weight computed INLINE: w = exp(leaky(el[s][h] + er[d][h])).
// el (3.2MB) is an L2-resident gather; er[d][h] hoisted out of the loop.
// This deletes the 25.6MB wE write (place) + 25.6MB wE read (here).
// ---------------------------------------------------------------------------
__global__ __launch_bounds__(256) void agg_kernel(
    const __half* __restrict__ fs, const float* __restrict__ el,
    const float* __restrict__ er, const int* __restrict__ roff,
    const int* __restrict__ deg, const int* __restrict__ csr,
    float* __restrict__ out, int n)
{
    int lane = threadIdx.x & 63;
    int wv = threadIdx.x >> 6;
    int g = lane >> 4;                 // node group within wave
    int q = lane & 15;                 // sublane: dims [q*8, q*8+8)
    int h = q >> 1;                    // head of this lane's dims
    int node = blockIdx.x * 16 + wv * 4 + g;
    bool alive = node < n;
    int start = 0, d = 0;
    float er8 = 0.f;
    if (alive) {
        start = roff[node];
        d = deg[node];
        er8 = er[(size_t)node * 8 + h];
    }

    float acc[8] = {0.f, 0.f, 0.f, 0.f, 0.f, 0.f, 0.f, 0.f};
    float wsum = 0.f;
    int i = 0;
    for (; i + 4 <= d; i += 4) {
        int s[4]; float ex[4]; uint4 v[4];
#pragma unroll
        for (int j = 0; j < 4; ++j)
            s[j] = __builtin_nontemporal_load(csr + start + i + j);
#pragma unroll
        for (int j = 0; j < 4; ++j)
            ex[j] = el[(size_t)s[j] * 8 + h];
#pragma unroll
        for (int j = 0; j < 4; ++j)
            v[j] = *(const uint4*)(fs + (size_t)s[j] * 128 + q * 8);
#pragma unroll
        for (int j = 0; j < 4; ++j) {
            float x = ex[j] + er8;
            x = (x < 0.f) ? SLOPE * x : x;
            float w = __expf(x);
            const __half* hp = (const __half*)&v[j];
#pragma unroll
            for (int k = 0; k < 8; ++k)
                acc[k] = fmaf(w, (float)hp[k], acc[k]);   // v_fma_mix
            wsum += w;
        }
    }
    for (; i < d; ++i) {
        int s0 = __builtin_nontemporal_load(csr + start + i);
        float x = el[(size_t)s0 * 8 + h] + er8;
        x = (x < 0.f) ? SLOPE * x : x;
        float w0 = __expf(x);
        uint4 v0 = *(const uint4*)(fs + (size_t)s0 * 128 + q * 8);
        const __half* hp = (const __half*)&v0;
#pragma unroll
        for (int k = 0; k < 8; ++k)
            acc[k] = fmaf(w0, (float)hp[k], acc[k]);
        wsum += w0;
    }
    if (alive) {
        float inv = (d > 0) ? 1.0f / wsum : 0.f;
        f32x4 o0 = {acc[0] * inv, acc[1] * inv, acc[2] * inv, acc[3] * inv};
        f32x4 o1 = {acc[4] * inv, acc[5] * inv, acc[6] * inv, acc[7] * inv};
        __builtin_nontemporal_store(o0, (f32x4*)(out + (size_t)node * 128 + q * 8));
        __builtin_nontemporal_store(o1, (f32x4*)(out + (size_t)node * 128 + q * 8 + 4));
    }
}

// ---------------------------------------------------------------------------
extern "C" void kernel_launch(void* const* d_in, const int* in_sizes, int n_in,
                              void* d_out, int out_size, void* d_ws, size_t ws_size,
                              hipStream_t stream) {
    const float* feat_src = (const float*)d_in[0];
    const float* feat_dst = (const float*)d_in[1];
    const float* feat_rel = (const float*)d_in[2];
    const float* W_src    = (const float*)d_in[3];
    const float* b_src    = (const float*)d_in[4];
    const float* W_dst    = (const float*)d_in[5];
    const float* b_dst    = (const float*)d_in[6];
    const float* W_rel    = (const float*)d_in[7];
    const float* b_rel    = (const float*)d_in[8];
    const int*   src_idx  = (const int*)d_in[9];
    const int*   dst_idx  = (const int*)d_in[10];
    float* out = (float*)d_out;

    int n_src = in_sizes[0] / 128;
    int n_dst = in_sizes[1] / 128;
    int ne    = in_sizes[9];

    char* w = (char*)d_ws;
    auto alloc = [&](size_t b) { char* p = w; w += (b + 255) & ~(size_t)255; return p; };
    __half* fs   = (__half*)alloc((size_t)n_src * 128 * 2);
    float*  el   = (float*)alloc((size_t)n_src * 8 * 4);
    float*  er   = (float*)alloc((size_t)n_dst * 8 * 4);
    float*  attn = (float*)alloc(256 * 4);
    unsigned short* WtS = (unsigned short*)alloc(128 * 128 * 2);
    unsigned short* WtD = (unsigned short*)alloc(128 * 128 * 2);
    int*    deg  = (int*)alloc((size_t)n_dst * 8);   // deg + ncur contiguous
    int*    ncur = deg + n_dst;
    int*    excl = (int*)alloc((size_t)n_dst * 4);
    int*    bsum = (int*)alloc(512 * 4);
    int*    roff = (int*)alloc(((size_t)n_dst + 1) * 4);
    int*    csr  = (int*)alloc((size_t)ne * 4);

    (void)hipMemsetAsync(deg, 0, (size_t)n_dst * 8, stream);  // deg + ncur

    int nbdeg = (ne + 255) / 256;
    prep_kernel<<<129 + nbdeg, 256, 0, stream>>>(
        feat_rel, W_rel, b_rel, attn, W_src, WtS, W_dst, WtD, dst_idx, deg, ne);

    int nbs = (n_src + 63) / 64, nbd = (n_dst + 63) / 64;
    gemm_mfma_kernel<<<nbs + nbd, 256, 0, stream>>>(
        feat_src, WtS, b_src, feat_dst, WtD, b_dst, attn,
        fs, el, er, n_src, n_dst, nbs);

    int nb = (n_dst + 255) / 256;
    scan1<<<nb, 256, 0, stream>>>(deg, excl, bsum, n_dst);
    scan2<<<1, 512, 0, stream>>>(bsum, nb);
    scan3<<<nb, 256, 0, stream>>>(excl, bsum, roff, n_dst);

    scatter_kernel<<<(ne + 255) / 256, 256, 0, stream>>>(
        src_idx, dst_idx, roff, ncur, csr, ne);

    agg_kernel<<<(n_dst + 15) / 16, 256, 0, stream>>>(
        fs, el, er, roff, deg, csr, out, n_dst);
}

// Round 7
// 383.033 us; speedup vs baseline: 1.1184x; 1.1184x over previous
//
#include <hip/hip_runtime.h>
#include <hip/hip_fp16.h>
#include <hip/hip_bf16.h>

#define SLOPE 0.2f
#define EPB 4096   // edges per block in part_kernel (16/thread)
#define LDA 136    // padded LDS row (bf16 elems): 272B stride -> 2-way-free banks

typedef short bf16x8 __attribute__((ext_vector_type(8)));
typedef float f32x4 __attribute__((ext_vector_type(4)));

__device__ __forceinline__ unsigned short f2bf(float x) {
    unsigned u = __float_as_uint(x);
    u += 0x7FFFu + ((u >> 16) & 1u);     // RNE
    return (unsigned short)(u >> 16);
}

// ---------------------------------------------------------------------------
// prep fused: blocks 0..63 W_src->bf16^T, 64..127 W_dst->bf16^T, 128 attn,
// 129.. degree atomics (deg pre-zeroed by memset on same stream).
// ---------------------------------------------------------------------------
__global__ void prep_kernel(const float* __restrict__ feat_rel,
                            const float* __restrict__ W_rel,
                            const float* __restrict__ b_rel,
                            float* __restrict__ attn,
                            const float* __restrict__ W_src,
                            unsigned short* __restrict__ WtS,
                            const float* __restrict__ W_dst,
                            unsigned short* __restrict__ WtD,
                            const int* __restrict__ dst_idx,
                            int* __restrict__ deg, int ne) {
    int bx = blockIdx.x;
    if (bx < 128) {
        const float* W = (bx < 64) ? W_src : W_dst;
        unsigned short* Wt = (bx < 64) ? WtS : WtD;
        int t = (bx & 63) * 256 + threadIdx.x;   // 16384
        int n = t >> 7, k = t & 127;
        Wt[n * 128 + k] = f2bf(W[k * 128 + n]);
    } else if (bx == 128) {
        int j = threadIdx.x;            // 0..255
        float acc = b_rel[j];
        for (int d = 0; d < 128; ++d)
            acc = fmaf(feat_rel[d], W_rel[d * 256 + j], acc);
        attn[j] = acc;
    } else {
        int e = (bx - 129) * 256 + threadIdx.x;
        if (e < ne) atomicAdd(&deg[dst_idx[e]], 1);
    }
}

// ---------------------------------------------------------------------------
// MFMA GEMM (both projections in one launch): blocks [0,nbs) do feat_src,
// [nbs,..) feat_dst. 64 rows x 128 cols per block, fused epilogue:
// fs fp16 store + e[row][h] = sum_d f*attn. 4 waves; wave wv owns cols wv*32..+31.
// mfma_f32_16x16x32_bf16: C/D col=lane&15, row=quad*4+reg (m89-verified).
// ---------------------------------------------------------------------------
__global__ __launch_bounds__(256) void gemm_mfma_kernel(
    const float* __restrict__ featS, const unsigned short* __restrict__ WtS,
    const float* __restrict__ bS,
    const float* __restrict__ featD, const unsigned short* __restrict__ WtD,
    const float* __restrict__ bD,
    const float* __restrict__ attn, __half* __restrict__ fs,
    float* __restrict__ el, float* __restrict__ er,
    int Ms, int Md, int nbs)
{
    __shared__ unsigned short sA[64 * LDA];    // [row][k] bf16
    __shared__ unsigned short sB[128 * LDA];   // [n][k]  bf16

    int bx = blockIdx.x;
    const float* feat; const unsigned short* Wt; const float* bias;
    __half* f_out; float* e_out; int attn_off, M, row0;
    if (bx < nbs) {
        feat = featS; Wt = WtS; bias = bS; f_out = fs; e_out = el;
        attn_off = 0; M = Ms; row0 = bx * 64;
    } else {
        feat = featD; Wt = WtD; bias = bD; f_out = nullptr; e_out = er;
        attn_off = 16; M = Md; row0 = (bx - nbs) * 64;
    }

    int t = threadIdx.x;

    // stage A: 64x128 fp32 -> bf16; 2048 float4s / 256 thr = 8 each
#pragma unroll
    for (int i = 0; i < 8; ++i) {
        int idx = t + i * 256;
        int row = idx >> 5, k4 = idx & 31;
        int grow = row0 + row;
        float4 v = {0.f, 0.f, 0.f, 0.f};
        if (grow < M) v = *(const float4*)(feat + (size_t)grow * 128 + k4 * 4);
        ushort4 b;
        b.x = f2bf(v.x); b.y = f2bf(v.y); b.z = f2bf(v.z); b.w = f2bf(v.w);
        *(ushort4*)&sA[row * LDA + k4 * 4] = b;   // 8B aligned (272B rows)
    }
    // stage B: Wt bf16 128x128 -> padded LDS; 2048 16B chunks / 256 = 8 each
#pragma unroll
    for (int i = 0; i < 8; ++i) {
        int idx = t + i * 256;
        int n = idx >> 4, koff = (idx & 15) * 8;
        *(uint4*)&sB[n * LDA + koff] = *(const uint4*)&Wt[n * 128 + koff];
    }
    __syncthreads();

    int wv = t >> 6, lane = t & 63;
    int m = lane & 15, quad = lane >> 4;
    int n0 = wv * 32;

    f32x4 acc[2][4];
#pragma unroll
    for (int ct = 0; ct < 2; ++ct)
#pragma unroll
        for (int rt = 0; rt < 4; ++rt) acc[ct][rt] = (f32x4){0.f, 0.f, 0.f, 0.f};

#pragma unroll
    for (int ks = 0; ks < 4; ++ks) {
        bf16x8 a[4], b[2];
#pragma unroll
        for (int rt = 0; rt < 4; ++rt)
            a[rt] = *(const bf16x8*)&sA[(rt * 16 + m) * LDA + ks * 32 + quad * 8];
#pragma unroll
        for (int ct = 0; ct < 2; ++ct)
            b[ct] = *(const bf16x8*)&sB[(n0 + ct * 16 + m) * LDA + ks * 32 + quad * 8];
#pragma unroll
        for (int ct = 0; ct < 2; ++ct)
#pragma unroll
            for (int rt = 0; rt < 4; ++rt)
                acc[ct][rt] = __builtin_amdgcn_mfma_f32_16x16x32_bf16(
                    a[rt], b[ct], acc[ct][rt], 0, 0, 0);
    }

    // epilogue
#pragma unroll
    for (int ct = 0; ct < 2; ++ct) {
        int gcol = n0 + ct * 16 + m;
        int h = gcol >> 4;
        float bias_v = bias[gcol];
        float attn_v = attn[h * 32 + attn_off + (gcol & 15)];
#pragma unroll
        for (int rt = 0; rt < 4; ++rt) {
            f32x4 c = acc[ct][rt];
#pragma unroll
            for (int r = 0; r < 4; ++r) {
                float v = c[r] + bias_v;
                int grow = row0 + rt * 16 + quad * 4 + r;
                float p = v * attn_v;
                p += __shfl_xor(p, 1);
                p += __shfl_xor(p, 2);
                p += __shfl_xor(p, 4);
                p += __shfl_xor(p, 8);
                if (grow < M) {
                    if (f_out) f_out[(size_t)grow * 128 + gcol] = __float2half(v);
                    if (m == 0) e_out[(size_t)grow * 8 + h] = p;
                }
            }
        }
    }
}

// ---------------------------------------------------------------------------
// CSR offsets: scan over deg
// ---------------------------------------------------------------------------
__global__ void scan1(const int* __restrict__ deg, int* __restrict__ excl,
                      int* __restrict__ bsum, int n) {
    __shared__ int tmp[256];
    int t = threadIdx.x;
    int i = blockIdx.x * 256 + t;
    int v = (i < n) ? deg[i] : 0;
    tmp[t] = v;
    __syncthreads();
    for (int off = 1; off < 256; off <<= 1) {
        int x = 0;
        if (t >= off) x = tmp[t - off];
        __syncthreads();
        tmp[t] += x;
        __syncthreads();
    }
    if (i < n) excl[i] = tmp[t] - v;
    if (t == 255) bsum[blockIdx.x] = tmp[255];
}

__global__ void scan2(int* __restrict__ bsum, int nb) {
    __shared__ int tmp[512];
    int t = threadIdx.x;
    int v = (t < nb) ? bsum[t] : 0;
    tmp[t] = v;
    __syncthreads();
    for (int off = 1; off < 512; off <<= 1) {
        int x = 0;
        if (t >= off) x = tmp[t - off];
        __syncthreads();
        tmp[t] += x;
        __syncthreads();
    }
    if (t < nb) bsum[t] = tmp[t] - v;
}

// scan3 + initcur fused: roff[i] = excl[i] + bsum[block]; bucket starts -> bcur
__global__ void scan3(const int* __restrict__ excl, const int* __restrict__ bsum,
                      int* __restrict__ roff, int* __restrict__ bcur, int n) {
    int i = blockIdx.x * 256 + threadIdx.x;
    if (i < n) {
        int v = excl[i] + bsum[blockIdx.x];
        roff[i] = v;
        if ((i & 127) == 0) bcur[i >> 7] = v;
    }
}

// ---------------------------------------------------------------------------
// Pass 1: LDS-histogram radix partition of edges into dst-buckets.
// Payload packed to 4B: src (20 bits) | (dst&127)<<20. Writes confined to
// live bucket windows (the R3/R6 global scatters lost 4-17x write-amp here).
// ---------------------------------------------------------------------------
__global__ __launch_bounds__(256) void part_kernel(
    const int* __restrict__ src_idx, const int* __restrict__ dst_idx,
    int* __restrict__ bcur, int* __restrict__ part, int ne)
{
    __shared__ int hist[1024];
    __shared__ int base[1024];
    int tid = threadIdx.x;
    for (int i = tid; i < 1024; i += 256) hist[i] = 0;
    int e0 = blockIdx.x * EPB;
    int myS[16], myD[16];
    __syncthreads();
#pragma unroll
    for (int i = 0; i < 16; ++i) {
        int e = e0 + i * 256 + tid;
        if (e < ne) {
            myS[i] = src_idx[e];
            myD[i] = dst_idx[e];
            atomicAdd(&hist[myD[i] >> 7], 1);
        } else myD[i] = -1;
    }
    __syncthreads();
    for (int b = tid; b < 1024; b += 256) {
        int c = hist[b];
        if (c > 0) {
            base[b] = atomicAdd(&bcur[b], c);
            hist[b] = 0;
        }
    }
    __syncthreads();
#pragma unroll
    for (int i = 0; i < 16; ++i) {
        if (myD[i] >= 0) {
            int b = myD[i] >> 7;
            int slot = base[b] + atomicAdd(&hist[b], 1);
            part[slot] = myS[i] | ((myD[i] & 127) << 20);
        }
    }
}

// ---------------------------------------------------------------------------
// Pass 2 (csr only — no wE/el/er work; that moved inline into agg):
// one block OWNS one bucket's CSR window; LDS curs atomics; csr writes land
// within the bucket's ~8KB window (full-line write-back).
// ---------------------------------------------------------------------------
__global__ __launch_bounds__(256) void place_kernel(
    const int* __restrict__ part, const int* __restrict__ roff,
    int* __restrict__ csr, int n_dst, int ne)
{
    int b = blockIdx.x;
    int node0 = b << 7;
    int tid = threadIdx.x;
    __shared__ int curs[128];
    __shared__ int roffs[128];
    int nend = node0 + 128; if (nend > n_dst) nend = n_dst;
    if (tid < 128) {
        curs[tid] = 0;
        roffs[tid] = (node0 + tid < n_dst) ? roff[node0 + tid] : 0;
    }
    int pstart = roff[node0];
    int pend = (nend >= n_dst) ? ne : roff[nend];
    __syncthreads();

    for (int pi = pstart + tid; pi < pend; pi += 256) {
        int val = part[pi];                 // coalesced
        int s = val & 0xFFFFF;
        int dl = val >> 20;                 // dst & 127
        int fine = atomicAdd(&curs[dl], 1);
        csr[roffs[dl] + fine] = s;
    }
}

// ---------------------------------------------------------------------------
// Aggregation: 16 lanes per dst node (4 nodes/wave, 16 nodes/block).
// Lane q owns dims [q*8,q*8+8) -> one dwordx4 gather/edge/lane; head = q>>1.
// Edge weight computed INLINE: w = exp(leaky(el[s][h] + er[d][h])).
// el (3.2MB) is an L2-resident gather; er[d][h] hoisted out of the loop.
// ---------------------------------------------------------------------------
__global__ __launch_bounds__(256) void agg_kernel(
    const __half* __restrict__ fs, const float* __restrict__ el,
    const float* __restrict__ er, const int* __restrict__ roff,
    const int* __restrict__ deg, const int* __restrict__ csr,
    float* __restrict__ out, int n)
{
    int lane = threadIdx.x & 63;
    int wv = threadIdx.x >> 6;
    int g = lane >> 4;                 // node group within wave
    int q = lane & 15;                 // sublane: dims [q*8, q*8+8)
    int h = q >> 1;                    // head of this lane's dims
    int node = blockIdx.x * 16 + wv * 4 + g;
    bool alive = node < n;
    int start = 0, d = 0;
    float er8 = 0.f;
    if (alive) {
        start = roff[node];
        d = deg[node];
        er8 = er[(size_t)node * 8 + h];
    }

    float acc[8] = {0.f, 0.f, 0.f, 0.f, 0.f, 0.f, 0.f, 0.f};
    float wsum = 0.f;
    int i = 0;
    for (; i + 4 <= d; i += 4) {
        int s[4]; float ex[4]; uint4 v[4];
#pragma unroll
        for (int j = 0; j < 4; ++j)
            s[j] = __builtin_nontemporal_load(csr + start + i + j);
#pragma unroll
        for (int j = 0; j < 4; ++j)
            ex[j] = el[(size_t)s[j] * 8 + h];
#pragma unroll
        for (int j = 0; j < 4; ++j)
            v[j] = *(const uint4*)(fs + (size_t)s[j] * 128 + q * 8);
#pragma unroll
        for (int j = 0; j < 4; ++j) {
            float x = ex[j] + er8;
            x = (x < 0.f) ? SLOPE * x : x;
            float w = __expf(x);
            const __half* hp = (const __half*)&v[j];
#pragma unroll
            for (int k = 0; k < 8; ++k)
                acc[k] = fmaf(w, (float)hp[k], acc[k]);   // v_fma_mix
            wsum += w;
        }
    }
    for (; i < d; ++i) {
        int s0 = __builtin_nontemporal_load(csr + start + i);
        float x = el[(size_t)s0 * 8 + h] + er8;
        x = (x < 0.f) ? SLOPE * x : x;
        float w0 = __expf(x);
        uint4 v0 = *(const uint4*)(fs + (size_t)s0 * 128 + q * 8);
        const __half* hp = (const __half*)&v0;
#pragma unroll
        for (int k = 0; k < 8; ++k)
            acc[k] = fmaf(w0, (float)hp[k], acc[k]);
        wsum += w0;
    }
    if (alive) {
        float inv = (d > 0) ? 1.0f / wsum : 0.f;
        f32x4 o0 = {acc[0] * inv, acc[1] * inv, acc[2] * inv, acc[3] * inv};
        f32x4 o1 = {acc[4] * inv, acc[5] * inv, acc[6] * inv, acc[7] * inv};
        __builtin_nontemporal_store(o0, (f32x4*)(out + (size_t)node * 128 + q * 8));
        __builtin_nontemporal_store(o1, (f32x4*)(out + (size_t)node * 128 + q * 8 + 4));
    }
}

// ---------------------------------------------------------------------------
extern "C" void kernel_launch(void* const* d_in, const int* in_sizes, int n_in,
                              void* d_out, int out_size, void* d_ws, size_t ws_size,
                              hipStream_t stream) {
    const float* feat_src = (const float*)d_in[0];
    const float* feat_dst = (const float*)d_in[1];
    const float* feat_rel = (const float*)d_in[2];
    const float* W_src    = (const float*)d_in[3];
    const float* b_src    = (const float*)d_in[4];
    const float* W_dst    = (const float*)d_in[5];
    const float* b_dst    = (const float*)d_in[6];
    const float* W_rel    = (const float*)d_in[7];
    const float* b_rel    = (const float*)d_in[8];
    const int*   src_idx  = (const int*)d_in[9];
    const int*   dst_idx  = (const int*)d_in[10];
    float* out = (float*)d_out;

    int n_src = in_sizes[0] / 128;
    int n_dst = in_sizes[1] / 128;
    int ne    = in_sizes[9];
    int nbuck = (n_dst + 127) >> 7;

    char* w = (char*)d_ws;
    auto alloc = [&](size_t b) { char* p = w; w += (b + 255) & ~(size_t)255; return p; };
    __half* fs   = (__half*)alloc((size_t)n_src * 128 * 2);
    float*  el   = (float*)alloc((size_t)n_src * 8 * 4);
    float*  er   = (float*)alloc((size_t)n_dst * 8 * 4);
    float*  attn = (float*)alloc(256 * 4);
    unsigned short* WtS = (unsigned short*)alloc(128 * 128 * 2);
    unsigned short* WtD = (unsigned short*)alloc(128 * 128 * 2);
    int*    deg  = (int*)alloc((size_t)n_dst * 4);
    int*    excl = (int*)alloc((size_t)n_dst * 4);
    int*    bsum = (int*)alloc(512 * 4);
    int*    roff = (int*)alloc(((size_t)n_dst + 1) * 4);
    int*    bcur = (int*)alloc(1024 * 4);
    int*    csr  = (int*)alloc((size_t)ne * 4);
    int*    part = (int*)alloc((size_t)ne * 4);

    (void)hipMemsetAsync(deg, 0, (size_t)n_dst * 4, stream);

    int nbdeg = (ne + 255) / 256;
    prep_kernel<<<129 + nbdeg, 256, 0, stream>>>(
        feat_rel, W_rel, b_rel, attn, W_src, WtS, W_dst, WtD, dst_idx, deg, ne);

    int nbs = (n_src + 63) / 64, nbd = (n_dst + 63) / 64;
    gemm_mfma_kernel<<<nbs + nbd, 256, 0, stream>>>(
        feat_src, WtS, b_src, feat_dst, WtD, b_dst, attn,
        fs, el, er, n_src, n_dst, nbs);

    int nb = (n_dst + 255) / 256;
    scan1<<<nb, 256, 0, stream>>>(deg, excl, bsum, n_dst);
    scan2<<<1, 512, 0, stream>>>(bsum, nb);
    scan3<<<nb, 256, 0, stream>>>(excl, bsum, roff, bcur, n_dst);

    part_kernel<<<(ne + EPB - 1) / EPB, 256, 0, stream>>>(src_idx, dst_idx, bcur, part, ne);
    place_kernel<<<nbuck, 256, 0, stream>>>(part, roff, csr, n_dst, ne);

    agg_kernel<<<(n_dst + 15) / 16, 256, 0, stream>>>(
        fs, el, er, roff, deg, csr, out, n_dst);
}